// Round 5
// baseline (111.797 us; speedup 1.0000x reference)
//
#include <hip/hip_runtime.h>
#include <hip/hip_bf16.h>

// Problem constants (B=16, Q=900, C=512, T=40, L=91)
#define BQ   14400      // B*Q rows
#define BT   640        // B*T cols
#define CD   512        // class dim (K of the GEMM)
#define LD   91
#define TD   40

typedef __attribute__((ext_vector_type(8))) short short8;
typedef __attribute__((ext_vector_type(4))) float f32x4;

// async global->LDS, 16 B per lane; LDS dest = wave-uniform base + lane*16
__device__ __forceinline__ void gload_lds16(const void* g, void* lds) {
    __builtin_amdgcn_global_load_lds(
        (const __attribute__((address_space(1))) unsigned int*)g,
        (__attribute__((address_space(3))) unsigned int*)lds, 16, 0, 0);
}

// ---------------------------------------------------------------------------
// Pass 1: normalized lm, bf16, kb-major fragment layout:
//   Bf[kb][w][nf][lane][8]:  kb=K/32 step, w=wave (80-col slice), nf=16-col
//   frag.  col = w*80 + nf*16 + (lane&15),  k = kb*32 + (lane>>4)*8 + j.
//   One kb slice = 40 KB contiguous -> single linear LDS stage.
// ---------------------------------------------------------------------------
__global__ __launch_bounds__(256) void build_lmfrag_kernel(
    const float* __restrict__ label_maps,   // [16][91][512]
    const int* __restrict__ class_labels,   // [640]
    __hip_bfloat16* __restrict__ Bf)        // [16][8][5][64][8]
{
    __shared__ float rows[16][512];         // 32 KB
    __shared__ float inv[16];
    int nt = blockIdx.x;                    // 16-col tile, 0..39
    int t  = threadIdx.x;

    #pragma unroll
    for (int e = 0; e < 8; ++e) {
        int idx4 = t + e * 256;             // float4 index 0..2047
        int r    = idx4 >> 7;
        int c4   = idx4 & 127;
        int j    = nt * 16 + r;
        int b    = j / TD;
        int cls  = class_labels[j];
        float4 v = *(const float4*)(label_maps + ((size_t)(b * LD + cls) * CD) + c4 * 4);
        *(float4*)(&rows[r][c4 * 4]) = v;
    }
    __syncthreads();

    int w = t >> 6, l = t & 63;
    #pragma unroll
    for (int q = 0; q < 4; ++q) {
        int r = w * 4 + q;
        float s = 0.f;
        #pragma unroll
        for (int e = 0; e < 8; ++e) s += rows[r][l + e * 64];
        #pragma unroll
        for (int off = 32; off >= 1; off >>= 1) s += __shfl_down(s, off, 64);
        if (l == 0) inv[r] = __builtin_amdgcn_rcpf(s);
    }
    __syncthreads();

    int w5 = nt / 5, nf5 = nt % 5;
    #pragma unroll
    for (int e = 0; e < 4; ++e) {
        int sc = t + e * 256;               // 0..1023
        int kb = sc >> 6;
        int ln = sc & 63;
        int o  = ln >> 4;
        int rr = ln & 15;
        float scale = inv[rr];
        union { __hip_bfloat16 h[8]; uint4 u; } pk;
        #pragma unroll
        for (int j2 = 0; j2 < 8; ++j2)
            pk.h[j2] = __float2bfloat16(rows[rr][kb * 32 + o * 8 + j2] * scale);
        size_t chunk = ((size_t)kb * 8 + w5) * 5 + nf5;
        *(uint4*)((char*)Bf + (chunk * 64 + ln) * 16) = pk.u;
    }
}

// ---------------------------------------------------------------------------
// focal term: pos - neg via softplus identity (exact; no eps needed |x|<18)
// ---------------------------------------------------------------------------
__device__ __forceinline__ float focal_term(float x)
{
    x = fminf(fmaxf(x, -18.0f), 18.0f);
    float q   = __expf(-x);                       // e^-x
    float s   = 1.0f + q;
    float p   = __builtin_amdgcn_rcpf(s);         // sigmoid(x)
    float spn = __logf(s);                        // softplus(-x) = -log p
    float omp = q * p;                            // 1 - p
    float pos = 0.25f * omp * omp * spn;
    float neg = 0.75f * p * p * (x + spn);
    return pos - neg;
}

// ---------------------------------------------------------------------------
// Fused main kernel. Grid 225, 512 threads (8 waves), 1 block/CU.
//   Wave w owns cols [w*80, w*80+80): acc[4 rf][5 nf] (80 VGPR). B dedup'd.
//   B staged per kb through LDS (double-buffered, global_load_lds w=16,
//   T3 minimum-2-phase: STAGE(kb+1); consume kb; barrier).
//   A (focal) computed once into LDS (64x512 bf16, octet-XOR swizzled).
// ---------------------------------------------------------------------------
__global__ __launch_bounds__(512, 2) void fused_cost_kernel(
    const float* __restrict__ logits,       // [14400][512]
    const float* __restrict__ pred_boxes,   // [14400][4]
    const __hip_bfloat16* __restrict__ Bf,  // [16][8][5][64][8]
    const float* __restrict__ tboxes,       // [640][4]
    float* __restrict__ out)                // [14400][640]
{
    __shared__ __align__(16) short A[64][512];      // 64 KB, swizzled octets
    __shared__ __align__(16) short Bb[2][20480];    // 2 x 40 KB
    __shared__ float pB[64][4];

    int t  = threadIdx.x;
    int m0 = blockIdx.x * 64;
    int l    = t & 63;
    int w    = t >> 6;                      // 0..7
    int lrow = l & 15;
    int kg   = l >> 4;
    int r7a  = lrow & 7;

    // ---- STAGE kb=0 into Bb[0] (async; focal phase covers the latency) ----
    #pragma unroll
    for (int i = 0; i < 5; ++i)
        gload_lds16((const char*)Bf + (size_t)((i * 8 + w) * 64 + l) * 16,
                    (char*)&Bb[0][0] + (i * 8 + w) * 1024);

    if (t < 64) *(float4*)(&pB[t][0]) = *(const float4*)(pred_boxes + (size_t)(m0 + t) * 4);

    // ---- focal: logits -> bf16 A tile in LDS (swizzled) ----
    {
        int row = t >> 3;                   // 0..63
        int sl  = t & 7;
        int r7  = row & 7;
        const float* lp = logits + (size_t)(m0 + row) * CD + sl * 16;
        #pragma unroll
        for (int i = 0; i < 4; ++i) {
            union { float4 v4[4]; float f[16]; } xu;
            #pragma unroll
            for (int j = 0; j < 4; ++j) xu.v4[j] = *(const float4*)(lp + i * 128 + j * 4);
            union { __hip_bfloat16 h[16]; uint4 u[2]; } pk;
            #pragma unroll
            for (int k = 0; k < 16; ++k) pk.h[k] = __float2bfloat16(focal_term(xu.f[k]));
            int o0 = sl * 2 + i * 16;       // octet index (16B units)
            *(uint4*)(&A[row][(o0 ^ r7) * 8])       = pk.u[0];
            *(uint4*)(&A[row][((o0 + 1) ^ r7) * 8]) = pk.u[1];
        }
    }
    __syncthreads();                        // A ready + Bb[0] staged (drain)

    // ---- K loop: double-buffered LDS B, prefetch-next / consume-current ----
    f32x4 acc[4][5] = {};
    #pragma unroll
    for (int kb = 0; kb < 16; ++kb) {
        const int cur = kb & 1;
        if (kb < 15) {
            const char* src = (const char*)Bf + (size_t)(kb + 1) * 40960;
            #pragma unroll
            for (int i = 0; i < 5; ++i)
                gload_lds16(src + (size_t)((i * 8 + w) * 64 + l) * 16,
                            (char*)&Bb[cur ^ 1][0] + (i * 8 + w) * 1024);
        }
        short8 a[4], b[5];
        #pragma unroll
        for (int rf = 0; rf < 4; ++rf)
            a[rf] = *(const short8*)(&A[rf * 16 + lrow][((kb * 4 + kg) ^ r7a) * 8]);
        #pragma unroll
        for (int nf = 0; nf < 5; ++nf)
            b[nf] = *(const short8*)(&Bb[cur][((w * 5 + nf) * 64 + l) * 8]);
        #pragma unroll
        for (int rf = 0; rf < 4; ++rf)
            #pragma unroll
            for (int nf = 0; nf < 5; ++nf)
                acc[rf][nf] = __builtin_amdgcn_mfma_f32_16x16x32_bf16(a[rf], b[nf], acc[rf][nf], 0, 0, 0);
        __syncthreads();                    // drains staged loads for kb+1
    }

    // ---- epilogue: hoist derived col params (5), loop row frags ----
    float tc[5][8];   // tcx,tcy,tw,th, tx0,ty0,tx1,ty1
    #pragma unroll
    for (int nf = 0; nf < 5; ++nf) {
        int cl = w * 80 + nf * 16 + lrow;
        float4 tb = *(const float4*)(tboxes + (size_t)cl * 4);
        tc[nf][0] = tb.x; tc[nf][1] = tb.y; tc[nf][2] = tb.z; tc[nf][3] = tb.w;
        tc[nf][4] = tb.x - 0.5f * tb.z;
        tc[nf][5] = tb.y - 0.5f * tb.w;
        tc[nf][6] = tb.x + 0.5f * tb.z;
        tc[nf][7] = tb.y + 0.5f * tb.w;
    }

    #pragma unroll
    for (int rf = 0; rf < 4; ++rf) {
        #pragma unroll
        for (int r = 0; r < 4; ++r) {
            int rl = rf * 16 + kg * 4 + r;
            float4 pb = *(const float4*)(&pB[rl][0]);
            float px0 = pb.x - 0.5f * pb.z, py0 = pb.y - 0.5f * pb.w;
            float px1 = pb.x + 0.5f * pb.z, py1 = pb.y + 0.5f * pb.w;
            float areaP = pb.z * pb.w;
            size_t orow = (size_t)(m0 + rl) * BT + w * 80 + lrow;
            #pragma unroll
            for (int nf = 0; nf < 5; ++nf) {
                const float* T = tc[nf];
                float bbox = fabsf(pb.x - T[0]) + fabsf(pb.y - T[1])
                           + fabsf(pb.z - T[2]) + fabsf(pb.w - T[3]);
                float iw = fminf(px1, T[6]) - fmaxf(px0, T[4]);
                float ih = fminf(py1, T[7]) - fmaxf(py0, T[5]);
                iw = fmaxf(iw, 0.0f); ih = fmaxf(ih, 0.0f);
                float inter = iw * ih;
                float uni   = areaP + T[2] * T[3] - inter;
                float ew = fmaxf(px1, T[6]) - fminf(px0, T[4]);
                float eh = fmaxf(py1, T[7]) - fminf(py0, T[5]);
                float areaE = ew * eh;
                float iou  = inter * __builtin_amdgcn_rcpf(uni);
                float gpen = (areaE - uni) * __builtin_amdgcn_rcpf(areaE);
                float giou = iou - gpen;
                float cls  = acc[rf][nf][r];
                out[orow + nf * 16] = 5.0f * bbox + 2.0f * cls - 2.0f * giou;
            }
        }
    }
}

// ---------------------------------------------------------------------------
extern "C" void kernel_launch(void* const* d_in, const int* in_sizes, int n_in,
                              void* d_out, int out_size, void* d_ws, size_t ws_size,
                              hipStream_t stream) {
    const float* logits       = (const float*)d_in[0];   // [16,900,512]
    const float* pred_boxes   = (const float*)d_in[1];   // [16,900,4]
    const float* label_maps   = (const float*)d_in[2];   // [16,91,512]
    const float* boxes        = (const float*)d_in[3];   // [16,40,4]
    const int*   class_labels = (const int*)d_in[4];     // [16,40]
    float* out = (float*)d_out;                          // [16,900,640]

    __hip_bfloat16* Bf = (__hip_bfloat16*)d_ws;          // 655 KB kb-major lm

    build_lmfrag_kernel<<<40, 256, 0, stream>>>(label_maps, class_labels, Bf);
    fused_cost_kernel<<<BQ / 64, 512, 0, stream>>>(logits, pred_boxes, Bf, boxes, out);
}

// Round 6
// 109.229 us; speedup vs baseline: 1.0235x; 1.0235x over previous
//
#include <hip/hip_runtime.h>
#include <hip/hip_bf16.h>

// Problem constants (B=16, Q=900, C=512, T=40, L=91)
#define BQ   14400      // B*Q rows
#define BT   640        // B*T cols
#define CD   512        // class dim (K of the GEMM)
#define LD   91
#define TD   40

typedef __attribute__((ext_vector_type(8))) short short8;
typedef __attribute__((ext_vector_type(4))) float f32x4;

// ---------------------------------------------------------------------------
// Pass 1: normalized lm, bf16, wave-major MFMA-fragment layout:
//   Bf[w][kb][nf][lane][8]:  w=0..7 (80-col wave slice), kb=0..15 (K/32),
//   nf=0..4 (16-col frag).  col = w*80 + nf*16 + (lane&15),
//   k = kb*32 + (lane>>4)*8 + j.  One (w,kb) group = 5 KB contiguous.
// ---------------------------------------------------------------------------
__global__ __launch_bounds__(256) void build_lmfrag_kernel(
    const float* __restrict__ label_maps,   // [16][91][512]
    const int* __restrict__ class_labels,   // [640]
    __hip_bfloat16* __restrict__ Bf)        // [8][16][5][64][8]
{
    __shared__ float rows[16][512];         // 32 KB
    __shared__ float inv[16];
    int nt = blockIdx.x;                    // 16-col tile, 0..39
    int t  = threadIdx.x;

    #pragma unroll
    for (int e = 0; e < 8; ++e) {
        int idx4 = t + e * 256;             // float4 index 0..2047
        int r    = idx4 >> 7;
        int c4   = idx4 & 127;
        int j    = nt * 16 + r;
        int b    = j / TD;
        int cls  = class_labels[j];
        float4 v = *(const float4*)(label_maps + ((size_t)(b * LD + cls) * CD) + c4 * 4);
        *(float4*)(&rows[r][c4 * 4]) = v;
    }
    __syncthreads();

    int w = t >> 6, l = t & 63;
    #pragma unroll
    for (int q = 0; q < 4; ++q) {
        int r = w * 4 + q;
        float s = 0.f;
        #pragma unroll
        for (int e = 0; e < 8; ++e) s += rows[r][l + e * 64];
        #pragma unroll
        for (int off = 32; off >= 1; off >>= 1) s += __shfl_down(s, off, 64);
        if (l == 0) inv[r] = __builtin_amdgcn_rcpf(s);
    }
    __syncthreads();

    int w5 = nt / 5, nf5 = nt % 5;
    #pragma unroll
    for (int e = 0; e < 4; ++e) {
        int sc = t + e * 256;               // 0..1023
        int kb = sc >> 6;
        int ln = sc & 63;
        int o  = ln >> 4;
        int rr = ln & 15;
        float scale = inv[rr];
        union { __hip_bfloat16 h[8]; uint4 u; } pk;
        #pragma unroll
        for (int j2 = 0; j2 < 8; ++j2)
            pk.h[j2] = __float2bfloat16(rows[rr][kb * 32 + o * 8 + j2] * scale);
        size_t chunk = ((size_t)w5 * 16 + kb) * 5 + nf5;
        *(uint4*)((char*)Bf + (chunk * 64 + ln) * 16) = pk.u;
    }
}

// ---------------------------------------------------------------------------
// focal term: pos - neg via softplus identity (exact; no eps needed |x|<18)
// ---------------------------------------------------------------------------
__device__ __forceinline__ float focal_term(float x)
{
    x = fminf(fmaxf(x, -18.0f), 18.0f);
    float q   = __expf(-x);                       // e^-x
    float s   = 1.0f + q;
    float p   = __builtin_amdgcn_rcpf(s);         // sigmoid(x)
    float spn = __logf(s);                        // softplus(-x) = -log p
    float omp = q * p;                            // 1 - p
    float pos = 0.25f * omp * omp * spn;
    float neg = 0.75f * p * p * (x + spn);
    return pos - neg;
}

// B-buffer load / consume macros — NAMED scalar buffers only (no arrays, no
// pointers): rule-#20-proof. All KB arguments are compile-time constants.
#define LOAD5(B0, B1, B2, B3, B4, KB)            \
    B0 = bw[((KB) * 5 + 0) * 64];                \
    B1 = bw[((KB) * 5 + 1) * 64];                \
    B2 = bw[((KB) * 5 + 2) * 64];                \
    B3 = bw[((KB) * 5 + 3) * 64];                \
    B4 = bw[((KB) * 5 + 4) * 64];

#define CONSUME5(B0, B1, B2, B3, B4, KB)                                          \
    {                                                                             \
        _Pragma("unroll")                                                         \
        for (int rf = 0; rf < 4; ++rf) {                                          \
            short8 aa = *(const short8*)(&A[rf * 16 + lrow]                       \
                                          [(((KB) * 4 + kg) ^ r7a) * 8]);         \
            acc[rf][0] = __builtin_amdgcn_mfma_f32_16x16x32_bf16(aa, B0, acc[rf][0], 0, 0, 0); \
            acc[rf][1] = __builtin_amdgcn_mfma_f32_16x16x32_bf16(aa, B1, acc[rf][1], 0, 0, 0); \
            acc[rf][2] = __builtin_amdgcn_mfma_f32_16x16x32_bf16(aa, B2, acc[rf][2], 0, 0, 0); \
            acc[rf][3] = __builtin_amdgcn_mfma_f32_16x16x32_bf16(aa, B3, acc[rf][3], 0, 0, 0); \
            acc[rf][4] = __builtin_amdgcn_mfma_f32_16x16x32_bf16(aa, B4, acc[rf][4], 0, 0, 0); \
        }                                                                         \
    }

// ---------------------------------------------------------------------------
// Fused main kernel. Grid 225, 512 threads (8 waves), 1 block/CU.
//   Wave w owns cols [w*80, w*80+80): acc[4 rf][5 nf] (80 VGPR). B dedup'd.
//   B: 2-deep register software pipeline (named bufs), barrier-free K loop.
//   A (focal) computed once into LDS (64x512 bf16, octet-XOR swizzled).
// ---------------------------------------------------------------------------
__global__ __launch_bounds__(512, 2) void fused_cost_kernel(
    const float* __restrict__ logits,       // [14400][512]
    const float* __restrict__ pred_boxes,   // [14400][4]
    const __hip_bfloat16* __restrict__ Bf,  // [8][16][5][64][8]
    const float* __restrict__ tboxes,       // [640][4]
    float* __restrict__ out)                // [14400][640]
{
    __shared__ __align__(16) short A[64][512];   // 64 KB, swizzled octets
    __shared__ float pB[64][4];

    int t  = threadIdx.x;
    int m0 = blockIdx.x * 64;
    int l    = t & 63;
    int w    = t >> 6;                      // 0..7
    int lrow = l & 15;
    int kg   = l >> 4;
    int r7a  = lrow & 7;

    // per-wave, per-lane B base (short8 units); frag (kb,nf) at +(kb*5+nf)*64
    const short8* bw = (const short8*)Bf + (size_t)w * 80 * 64 + l;

    // ---- prologue: issue kb0/kb1 loads; focal phase covers the latency ----
    short8 bA0, bA1, bA2, bA3, bA4;
    short8 bB0, bB1, bB2, bB3, bB4;
    LOAD5(bA0, bA1, bA2, bA3, bA4, 0)
    LOAD5(bB0, bB1, bB2, bB3, bB4, 1)

    if (t < 64) *(float4*)(&pB[t][0]) = *(const float4*)(pred_boxes + (size_t)(m0 + t) * 4);

    // ---- focal: logits -> bf16 A tile in LDS (swizzled) ----
    {
        int row = t >> 3;                   // 0..63
        int sl  = t & 7;
        int r7  = row & 7;
        const float* lp = logits + (size_t)(m0 + row) * CD + sl * 16;
        #pragma unroll
        for (int i = 0; i < 4; ++i) {
            union { float4 v4[4]; float f[16]; } xu;
            #pragma unroll
            for (int j = 0; j < 4; ++j) xu.v4[j] = *(const float4*)(lp + i * 128 + j * 4);
            union { __hip_bfloat16 h[16]; uint4 u[2]; } pk;
            #pragma unroll
            for (int k = 0; k < 16; ++k) pk.h[k] = __float2bfloat16(focal_term(xu.f[k]));
            int o0 = sl * 2 + i * 16;       // octet index (16B units)
            *(uint4*)(&A[row][(o0 ^ r7) * 8])       = pk.u[0];
            *(uint4*)(&A[row][((o0 + 1) ^ r7) * 8]) = pk.u[1];
        }
    }
    __syncthreads();                        // the only barrier

    // ---- barrier-free K loop: consume kb, reload same buffer with kb+2 ----
    f32x4 acc[4][5] = {};
    #pragma unroll
    for (int i = 0; i < 8; ++i) {
        CONSUME5(bA0, bA1, bA2, bA3, bA4, 2 * i)
        if (i < 7) { LOAD5(bA0, bA1, bA2, bA3, bA4, 2 * i + 2) }
        CONSUME5(bB0, bB1, bB2, bB3, bB4, 2 * i + 1)
        if (i < 7) { LOAD5(bB0, bB1, bB2, bB3, bB4, 2 * i + 3) }
    }

    // ---- epilogue: hoist derived col params (5), loop row frags ----
    float tc[5][8];   // tcx,tcy,tw,th, tx0,ty0,tx1,ty1
    #pragma unroll
    for (int nf = 0; nf < 5; ++nf) {
        int cl = w * 80 + nf * 16 + lrow;
        float4 tb = *(const float4*)(tboxes + (size_t)cl * 4);
        tc[nf][0] = tb.x; tc[nf][1] = tb.y; tc[nf][2] = tb.z; tc[nf][3] = tb.w;
        tc[nf][4] = tb.x - 0.5f * tb.z;
        tc[nf][5] = tb.y - 0.5f * tb.w;
        tc[nf][6] = tb.x + 0.5f * tb.z;
        tc[nf][7] = tb.y + 0.5f * tb.w;
    }

    #pragma unroll
    for (int rf = 0; rf < 4; ++rf) {
        #pragma unroll
        for (int r = 0; r < 4; ++r) {
            int rl = rf * 16 + kg * 4 + r;
            float4 pb = *(const float4*)(&pB[rl][0]);
            float px0 = pb.x - 0.5f * pb.z, py0 = pb.y - 0.5f * pb.w;
            float px1 = pb.x + 0.5f * pb.z, py1 = pb.y + 0.5f * pb.w;
            float areaP = pb.z * pb.w;
            size_t orow = (size_t)(m0 + rl) * BT + w * 80 + lrow;
            #pragma unroll
            for (int nf = 0; nf < 5; ++nf) {
                const float* T = tc[nf];
                float bbox = fabsf(pb.x - T[0]) + fabsf(pb.y - T[1])
                           + fabsf(pb.z - T[2]) + fabsf(pb.w - T[3]);
                float iw = fminf(px1, T[6]) - fmaxf(px0, T[4]);
                float ih = fminf(py1, T[7]) - fmaxf(py0, T[5]);
                iw = fmaxf(iw, 0.0f); ih = fmaxf(ih, 0.0f);
                float inter = iw * ih;
                float uni   = areaP + T[2] * T[3] - inter;
                float ew = fmaxf(px1, T[6]) - fminf(px0, T[4]);
                float eh = fmaxf(py1, T[7]) - fminf(py0, T[5]);
                float areaE = ew * eh;
                float iou  = inter * __builtin_amdgcn_rcpf(uni);
                float gpen = (areaE - uni) * __builtin_amdgcn_rcpf(areaE);
                float giou = iou - gpen;
                float cls  = acc[rf][nf][r];
                out[orow + nf * 16] = 5.0f * bbox + 2.0f * cls - 2.0f * giou;
            }
        }
    }
}

// ---------------------------------------------------------------------------
extern "C" void kernel_launch(void* const* d_in, const int* in_sizes, int n_in,
                              void* d_out, int out_size, void* d_ws, size_t ws_size,
                              hipStream_t stream) {
    const float* logits       = (const float*)d_in[0];   // [16,900,512]
    const float* pred_boxes   = (const float*)d_in[1];   // [16,900,4]
    const float* label_maps   = (const float*)d_in[2];   // [16,91,512]
    const float* boxes        = (const float*)d_in[3];   // [16,40,4]
    const int*   class_labels = (const int*)d_in[4];     // [16,40]
    float* out = (float*)d_out;                          // [16,900,640]

    __hip_bfloat16* Bf = (__hip_bfloat16*)d_ws;          // 655 KB wave-major lm

    build_lmfrag_kernel<<<40, 256, 0, stream>>>(label_maps, class_labels, Bf);
    fused_cost_kernel<<<BQ / 64, 512, 0, stream>>>(logits, pred_boxes, Bf, boxes, out);
}